// Round 6
// baseline (1789.608 us; speedup 1.0000x reference)
//
#include <hip/hip_runtime.h>
#include <hip/hip_bf16.h>
#include <math.h>

typedef __bf16 bf16_t;
typedef __bf16 bf16x4 __attribute__((ext_vector_type(4)));
typedef __bf16 bf16x8 __attribute__((ext_vector_type(8)));
typedef float f32x4 __attribute__((ext_vector_type(4)));

#define NEGBIG -3.0e38f

// ---------------------------------------------------------------------------
// Weight transpose+convert: W [K][N] fp32  ->  Wt [N][K] bf16  (per layer z)
// ---------------------------------------------------------------------------
__global__ void __launch_bounds__(256) tr_k(
    const float* __restrict__ W, bf16_t* __restrict__ Wt, int K, int N)
{
    __shared__ float T[32][33];
    const size_t per = (size_t)K * N;
    const float* Wl = W + blockIdx.z * per;
    bf16_t* Wtl = Wt + blockIdx.z * per;
    int n0 = blockIdx.x * 32, k0 = blockIdx.y * 32;
    int tx = threadIdx.x & 31, ty = threadIdx.x >> 5;   // 32 x 8
#pragma unroll
    for (int i = 0; i < 4; ++i)
        T[ty + 8 * i][tx] = Wl[(size_t)(k0 + ty + 8 * i) * N + n0 + tx];
    __syncthreads();
#pragma unroll
    for (int i = 0; i < 4; ++i)
        Wtl[(size_t)(n0 + ty + 8 * i) * K + k0 + tx] = (bf16_t)T[tx][ty + 8 * i];
}

// ---------------------------------------------------------------------------
// Fused LayerNorm + GEMM: C[M,N] = LN(X)[M,384] * Bt[N,384]^T + bias
// Phase 1: stage 64 fp32 rows -> bf16 LDS, per-row LN in place.
// Phase 2: dbuf BK=32 MFMA loop (A static in LDS, B global->LDS prefetch).
// MODE 0: QKV scatter; MODE 2: GELU(exact) -> bf16 store.
// ---------------------------------------------------------------------------
template <int MODE>
__global__ void __launch_bounds__(256) gemm_ln(
    const float* __restrict__ X, const bf16_t* __restrict__ Bt,
    const float* __restrict__ bias,
    const float* __restrict__ lg, const float* __restrict__ lb,
    int M, int N, bf16_t* __restrict__ outb,
    bf16_t* __restrict__ qb, bf16_t* __restrict__ kb, bf16_t* __restrict__ vtb)
{
    __shared__ alignas(16) bf16_t An[64][392];    // 50.2 KB, stride 784B
    __shared__ alignas(16) bf16_t Bs[2][64][40];  // 10.0 KB

    const int tid  = threadIdx.x;
    const int wave = tid >> 6, lane = tid & 63;
    const int m0 = blockIdx.y * 64, n0 = blockIdx.x * 64;
    const int rb = (wave >> 1) * 32, cb = (wave & 1) * 32;
    const int q4 = lane >> 4, mm = lane & 15;

    // B staging geometry (BK=32): 64 rows x 32 k per tile
    const int brow = tid >> 2;            // 0..63
    const int bcol = (tid & 3) * 8;       // 0..24
    const bf16_t* pB = Bt + (size_t)(n0 + brow) * 384 + bcol;

    bf16x8 vb = *(const bf16x8*)(pB);     // prologue load (overlaps LN phase)

    // ---- Phase 1: load X rows, convert to bf16 in LDS ----
#pragma unroll
    for (int i = 0; i < 24; ++i) {
        int flat = tid + i * 256;             // float4 index in 64x96 grid
        int row = flat / 96, c4 = (flat % 96) * 4;
        int grow = m0 + row;
        float4 v = make_float4(0.f, 0.f, 0.f, 0.f);
        if (grow < M) v = ((const float4*)(X + (size_t)grow * 384))[flat % 96];
        bf16x4 w = { (bf16_t)v.x, (bf16_t)v.y, (bf16_t)v.z, (bf16_t)v.w };
        *(bf16x4*)(&An[row][c4]) = w;
    }
    __syncthreads();

    // ---- per-row LN: 4 threads per row, 96 cols each ----
    {
        const int trow = tid >> 2, ti = tid & 3;
        float s = 0.f, s2 = 0.f;
#pragma unroll
        for (int j = 0; j < 12; ++j) {
            bf16x8 v = *(const bf16x8*)(&An[trow][ti * 96 + j * 8]);
#pragma unroll
            for (int e = 0; e < 8; ++e) { float f = (float)v[e]; s += f; s2 += f * f; }
        }
        s  += __shfl_xor(s, 1, 4);  s  += __shfl_xor(s, 2, 4);
        s2 += __shfl_xor(s2, 1, 4); s2 += __shfl_xor(s2, 2, 4);
        float mean = s * (1.0f / 384.0f);
        float var  = s2 * (1.0f / 384.0f) - mean * mean;
        float rstd = rsqrtf(fmaxf(var, 0.f) + 1e-6f);
#pragma unroll
        for (int j = 0; j < 12; ++j) {
            int c0 = ti * 96 + j * 8;
            bf16x8 v = *(const bf16x8*)(&An[trow][c0]);
            float4 g0 = *(const float4*)(lg + c0);
            float4 g1 = *(const float4*)(lg + c0 + 4);
            float4 b0 = *(const float4*)(lb + c0);
            float4 b1 = *(const float4*)(lb + c0 + 4);
            float gg[8] = { g0.x, g0.y, g0.z, g0.w, g1.x, g1.y, g1.z, g1.w };
            float bb[8] = { b0.x, b0.y, b0.z, b0.w, b1.x, b1.y, b1.z, b1.w };
            bf16x8 o;
#pragma unroll
            for (int e = 0; e < 8; ++e)
                o[e] = (bf16_t)(((float)v[e] - mean) * rstd * gg[e] + bb[e]);
            *(bf16x8*)(&An[trow][c0]) = o;
        }
    }
    __syncthreads();

    // ---- Phase 2: MFMA K-loop, BK=32, B double-buffered ----
    *(bf16x8*)(&Bs[0][brow][bcol]) = vb;
    f32x4 acc[2][2] = {};
    int cur = 0;
    for (int k0 = 0; k0 < 384; k0 += 32) {
        __syncthreads();
        const bool has_next = (k0 + 32 < 384);
        if (has_next) vb = *(const bf16x8*)(pB + k0 + 32);
        bf16x8 a0 = *(const bf16x8*)(&An[rb + mm][k0 + q4 * 8]);
        bf16x8 a1 = *(const bf16x8*)(&An[rb + 16 + mm][k0 + q4 * 8]);
        bf16x8 b0 = *(const bf16x8*)(&Bs[cur][cb + mm][q4 * 8]);
        bf16x8 b1 = *(const bf16x8*)(&Bs[cur][cb + 16 + mm][q4 * 8]);
        acc[0][0] = __builtin_amdgcn_mfma_f32_16x16x32_bf16(a0, b0, acc[0][0], 0, 0, 0);
        acc[0][1] = __builtin_amdgcn_mfma_f32_16x16x32_bf16(a0, b1, acc[0][1], 0, 0, 0);
        acc[1][0] = __builtin_amdgcn_mfma_f32_16x16x32_bf16(a1, b0, acc[1][0], 0, 0, 0);
        acc[1][1] = __builtin_amdgcn_mfma_f32_16x16x32_bf16(a1, b1, acc[1][1], 0, 0, 0);
        if (has_next) {
            int nxt = cur ^ 1;
            *(bf16x8*)(&Bs[nxt][brow][bcol]) = vb;
            cur = nxt;
        }
    }

#pragma unroll
    for (int i = 0; i < 2; ++i)
#pragma unroll
    for (int j = 0; j < 2; ++j) {
        int gc = n0 + cb + j * 16 + mm;
        float bv = bias[gc];
#pragma unroll
        for (int r = 0; r < 4; ++r) {
            int gr = m0 + rb + i * 16 + q4 * 4 + r;
            if (gr >= M) continue;
            float val = acc[i][j][r] + bv;
            if (MODE == 2) {
                float g = 0.5f * val * (1.0f + erff(val * 0.70710678118654752f));
                outb[(size_t)gr * N + gc] = (bf16_t)g;
            } else {  // QKV scatter
                int which = gc / 384, rem = gc % 384;
                int h = rem >> 6, d = rem & 63;
                int b = gr / 962, n = gr % 962;
                int bh = b * 6 + h;
                bf16_t bvv = (bf16_t)val;
                if (which == 0)      qb[((size_t)bh * 962 + n) * 64 + d] = bvv;
                else if (which == 1) kb[((size_t)bh * 962 + n) * 64 + d] = bvv;
                else                 vtb[((size_t)bh * 64 + d) * 992 + n] = bvv;
            }
        }
    }
}

// ---------------------------------------------------------------------------
// Split-K dbuf MFMA GEMM (proj / fc2): partial = A[M,ks:ks+KLEN] * Bt^T
// 64x64 tile, BK=64 double-buffered (round-4 core). Epilogue: atomicAdd into
// fp32 residual (bias added by z==0 only). A rows padded (no load guards).
// ---------------------------------------------------------------------------
template <int KLEN>
__global__ void __launch_bounds__(256) gemm_sp(
    const bf16_t* __restrict__ A, int lda,
    const bf16_t* __restrict__ Bt, int ldb,
    const float* __restrict__ bias, int M, int N,
    float* __restrict__ resid)
{
    __shared__ alignas(16) bf16_t As[2][64][72];
    __shared__ alignas(16) bf16_t Bs[2][64][72];

    const int tid  = threadIdx.x;
    const int wave = tid >> 6, lane = tid & 63;
    const int m0 = blockIdx.y * 64, n0 = blockIdx.x * 64;
    const int rb = (wave >> 1) * 32, cb = (wave & 1) * 32;
    const int q4 = lane >> 4, mm = lane & 15;
    const int ks = blockIdx.z * KLEN;

    const int lrow = tid >> 3;         // 0..31
    const int lcol = (tid & 7) * 8;    // 0..56

    const bf16_t* pA0 = A  + (size_t)(m0 + lrow) * lda + ks + lcol;
    const bf16_t* pA1 = pA0 + (size_t)32 * lda;
    const bf16_t* pB0 = Bt + (size_t)(n0 + lrow) * ldb + ks + lcol;
    const bf16_t* pB1 = pB0 + (size_t)32 * ldb;

    f32x4 acc[2][2] = {};
    bf16x8 va0, va1, vb0, vb1;

    va0 = *(const bf16x8*)(pA0);
    va1 = *(const bf16x8*)(pA1);
    vb0 = *(const bf16x8*)(pB0);
    vb1 = *(const bf16x8*)(pB1);
    *(bf16x8*)(&As[0][lrow][lcol])      = va0;
    *(bf16x8*)(&As[0][lrow + 32][lcol]) = va1;
    *(bf16x8*)(&Bs[0][lrow][lcol])      = vb0;
    *(bf16x8*)(&Bs[0][lrow + 32][lcol]) = vb1;

    int cur = 0;
    for (int k0 = 0; k0 < KLEN; k0 += 64) {
        __syncthreads();
        const bool has_next = (k0 + 64 < KLEN);
        if (has_next) {
            va0 = *(const bf16x8*)(pA0 + k0 + 64);
            va1 = *(const bf16x8*)(pA1 + k0 + 64);
            vb0 = *(const bf16x8*)(pB0 + k0 + 64);
            vb1 = *(const bf16x8*)(pB1 + k0 + 64);
        }
#pragma unroll
        for (int kc = 0; kc < 64; kc += 32) {
            bf16x8 a0 = *(const bf16x8*)(&As[cur][rb + mm][kc + q4 * 8]);
            bf16x8 a1 = *(const bf16x8*)(&As[cur][rb + 16 + mm][kc + q4 * 8]);
            bf16x8 b0 = *(const bf16x8*)(&Bs[cur][cb + mm][kc + q4 * 8]);
            bf16x8 b1 = *(const bf16x8*)(&Bs[cur][cb + 16 + mm][kc + q4 * 8]);
            acc[0][0] = __builtin_amdgcn_mfma_f32_16x16x32_bf16(a0, b0, acc[0][0], 0, 0, 0);
            acc[0][1] = __builtin_amdgcn_mfma_f32_16x16x32_bf16(a0, b1, acc[0][1], 0, 0, 0);
            acc[1][0] = __builtin_amdgcn_mfma_f32_16x16x32_bf16(a1, b0, acc[1][0], 0, 0, 0);
            acc[1][1] = __builtin_amdgcn_mfma_f32_16x16x32_bf16(a1, b1, acc[1][1], 0, 0, 0);
        }
        if (has_next) {
            int nxt = cur ^ 1;
            *(bf16x8*)(&As[nxt][lrow][lcol])      = va0;
            *(bf16x8*)(&As[nxt][lrow + 32][lcol]) = va1;
            *(bf16x8*)(&Bs[nxt][lrow][lcol])      = vb0;
            *(bf16x8*)(&Bs[nxt][lrow + 32][lcol]) = vb1;
            cur = nxt;
        }
    }

#pragma unroll
    for (int i = 0; i < 2; ++i)
#pragma unroll
    for (int j = 0; j < 2; ++j) {
        int gc = n0 + cb + j * 16 + mm;
        float bv = (blockIdx.z == 0) ? bias[gc] : 0.f;
#pragma unroll
        for (int r = 0; r < 4; ++r) {
            int gr = m0 + rb + i * 16 + q4 * 4 + r;
            if (gr >= M) continue;
            atomicAdd(&resid[(size_t)gr * N + gc], acc[i][j][r] + bv);
        }
    }
}

// ---------------------------------------------------------------------------
// Fused masked attention (round-5 vectorized-stats version).
// ---------------------------------------------------------------------------
__global__ void __launch_bounds__(256) attn_k(
    const bf16_t* __restrict__ qb, const bf16_t* __restrict__ kb,
    const bf16_t* __restrict__ vtb, bf16_t* __restrict__ attnout,
    float* __restrict__ attn_save)
{
    __shared__ alignas(16) bf16_t S[16][1000];

    const int tid  = threadIdx.x;
    const int wave = tid >> 6, lane = tid & 63;
    const int q4 = lane >> 4, mm = lane & 15;
    const int bh = blockIdx.y, qt = blockIdx.x;
    const int qrow0 = qt * 16;

    int qr = qrow0 + mm; if (qr > 961) qr = 961;
    const bf16_t* qptr = qb + ((size_t)bh * 962 + qr) * 64 + q4 * 8;
    bf16x8 aq0 = *(const bf16x8*)(qptr);
    bf16x8 aq1 = *(const bf16x8*)(qptr + 32);

    for (int ct = wave; ct < 61; ct += 4) {
        int kr = ct * 16 + mm; if (kr > 961) kr = 961;
        const bf16_t* kptr = kb + ((size_t)bh * 962 + kr) * 64 + q4 * 8;
        bf16x8 b0 = *(const bf16x8*)(kptr);
        bf16x8 b1 = *(const bf16x8*)(kptr + 32);
        f32x4 acc = {};
        acc = __builtin_amdgcn_mfma_f32_16x16x32_bf16(aq0, b0, acc, 0, 0, 0);
        acc = __builtin_amdgcn_mfma_f32_16x16x32_bf16(aq1, b1, acc, 0, 0, 0);
        int col = ct * 16 + mm;
#pragma unroll
        for (int r = 0; r < 4; ++r) {
            int row = q4 * 4 + r;
            if (col < 962) S[row][col] = (bf16_t)(acc[r] * 0.125f);
        }
    }
    for (int idx = tid; idx < 16 * 38; idx += 256) {
        int r = idx / 38, c = 962 + idx % 38;
        S[r][c] = (bf16_t)NEGBIG;
    }
    __syncthreads();

    const int trow = tid >> 4, ti = tid & 15;
    float e[8][8];
    float mx = NEGBIG;
#pragma unroll
    for (int t = 0; t < 8; ++t) {
        int c8 = ti * 8 + 128 * t;
        bf16x8 xv;
        if (c8 < 1000) xv = *(const bf16x8*)(&S[trow][c8]);
        else {
#pragma unroll
            for (int j = 0; j < 8; ++j) xv[j] = (bf16_t)NEGBIG;
        }
#pragma unroll
        for (int j = 0; j < 8; ++j) { e[t][j] = (float)xv[j]; mx = fmaxf(mx, e[t][j]); }
    }
#pragma unroll
    for (int off = 8; off > 0; off >>= 1) mx = fmaxf(mx, __shfl_xor(mx, off, 16));

    float sum = 0.f;
#pragma unroll
    for (int t = 0; t < 8; ++t)
#pragma unroll
    for (int j = 0; j < 8; ++j) {
        float ev = __expf(e[t][j] - mx);
        e[t][j] = ev;
        if (ev >= 0.1f) sum += ev;
    }
#pragma unroll
    for (int off = 8; off > 0; off >>= 1) sum += __shfl_xor(sum, off, 16);
    float inv = 1.0f / sum;

    int row_g = qrow0 + trow;
#pragma unroll
    for (int t = 0; t < 8; ++t) {
        int c8 = ti * 8 + 128 * t;
        if (c8 >= 1000) continue;
        bf16x8 pv;
#pragma unroll
        for (int j = 0; j < 8; ++j) {
            float pp = (e[t][j] >= 0.1f) ? e[t][j] * inv : 0.f;
            e[t][j] = pp;
            pv[j] = (bf16_t)pp;
        }
        *(bf16x8*)(&S[trow][c8]) = pv;
        if (attn_save && row_g < 962) {
#pragma unroll
            for (int j = 0; j < 8; ++j)
                if (c8 + j < 962)
                    attn_save[((size_t)bh * 962 + row_g) * 962 + c8 + j] = e[t][j];
        }
    }
    __syncthreads();

    const int wc0 = wave * 16;
    f32x4 o = {};
    for (int kc = 0; kc < 31; ++kc) {
        bf16x8 pa = *(const bf16x8*)(&S[mm][kc * 32 + q4 * 8]);
        bf16x8 vb = *(const bf16x8*)(vtb + ((size_t)bh * 64 + wc0 + mm) * 992 + kc * 32 + q4 * 8);
        o = __builtin_amdgcn_mfma_f32_16x16x32_bf16(pa, vb, o, 0, 0, 0);
    }
    int b = bh / 6, h = bh % 6;
#pragma unroll
    for (int r = 0; r < 4; ++r) {
        int qrr = qrow0 + q4 * 4 + r;
        if (qrr < 962)
            attnout[((size_t)(b * 962 + qrr)) * 384 + h * 64 + wc0 + mm] = (bf16_t)o[r];
    }
}

// ---------------------------------------------------------------------------
// Final LayerNorm: one wave per token, fp32 in/params, fp32 out
// ---------------------------------------------------------------------------
__global__ void __launch_bounds__(256) ln_k(
    const float* __restrict__ x, const float* __restrict__ g,
    const float* __restrict__ b, float* __restrict__ out)
{
    int t = blockIdx.x * 4 + (threadIdx.x >> 6);
    int lane = threadIdx.x & 63;
    const float* xp = x + (size_t)t * 384;
    float v[6];
    float s = 0.f;
#pragma unroll
    for (int i = 0; i < 6; ++i) { v[i] = xp[lane + 64 * i]; s += v[i]; }
    for (int off = 32; off > 0; off >>= 1) s += __shfl_xor(s, off);
    float mean = s * (1.0f / 384.0f);
    float s2 = 0.f;
#pragma unroll
    for (int i = 0; i < 6; ++i) { float d = v[i] - mean; s2 += d * d; }
    for (int off = 32; off > 0; off >>= 1) s2 += __shfl_xor(s2, off);
    float rstd = rsqrtf(s2 * (1.0f / 384.0f) + 1e-6f);
#pragma unroll
    for (int i = 0; i < 6; ++i) {
        int c = lane + 64 * i;
        out[(size_t)t * 384 + c] = (v[i] - mean) * rstd * g[c] + b[c];
    }
}

// ---------------------------------------------------------------------------
extern "C" void kernel_launch(void* const* d_in, const int* in_sizes, int n_in,
                              void* d_out, int out_size, void* d_ws, size_t ws_size,
                              hipStream_t stream)
{
    const float* xin    = (const float*)d_in[0];
    const float* w_qkv  = (const float*)d_in[1];
    const float* b_qkv  = (const float*)d_in[2];
    const float* w_proj = (const float*)d_in[3];
    const float* b_proj = (const float*)d_in[4];
    const float* ln1g   = (const float*)d_in[5];
    const float* ln1b   = (const float*)d_in[6];
    const float* ln2g   = (const float*)d_in[7];
    const float* ln2b   = (const float*)d_in[8];
    const float* w_fc1  = (const float*)d_in[9];
    const float* b_fc1  = (const float*)d_in[10];
    const float* w_fc2  = (const float*)d_in[11];
    const float* b_fc2  = (const float*)d_in[12];
    const float* lnfg   = (const float*)d_in[13];
    const float* lnfb   = (const float*)d_in[14];

    float* feats     = (float*)d_out;
    float* attn_save = feats + 738816;   // 2*962*384

    char* p = (char*)d_ws;
    auto alloc = [&](size_t bytes) {
        char* r = p;
        p += (bytes + 255) & ~(size_t)255;
        return r;
    };
    float*  x_f32   = (float*)alloc(1924ull * 384 * 4);
    bf16_t* qbuf    = (bf16_t*)alloc(12ull * 962 * 64 * 2);
    bf16_t* kbuf    = (bf16_t*)alloc(12ull * 962 * 64 * 2);
    bf16_t* vtbuf   = (bf16_t*)alloc(12ull * 64 * 992 * 2);
    bf16_t* attnout = (bf16_t*)alloc(1984ull * 384 * 2);    // rows padded
    bf16_t* mlp1    = (bf16_t*)alloc(1984ull * 1536 * 2);   // rows padded
    bf16_t* wt_qkv  = (bf16_t*)alloc(12ull * 1152 * 384 * 2);
    bf16_t* wt_proj = (bf16_t*)alloc(12ull * 384 * 384 * 2);
    bf16_t* wt_fc1  = (bf16_t*)alloc(12ull * 1536 * 384 * 2);
    bf16_t* wt_fc2  = (bf16_t*)alloc(12ull * 384 * 1536 * 2);

    // one-time per launch: weights -> bf16, transposed to [N][K]
    tr_k<<<dim3(36, 12, 12), dim3(256), 0, stream>>>(w_qkv,  wt_qkv,  384, 1152);
    tr_k<<<dim3(12, 12, 12), dim3(256), 0, stream>>>(w_proj, wt_proj, 384, 384);
    tr_k<<<dim3(48, 12, 12), dim3(256), 0, stream>>>(w_fc1,  wt_fc1,  384, 1536);
    tr_k<<<dim3(12, 48, 12), dim3(256), 0, stream>>>(w_fc2,  wt_fc2,  1536, 384);

    // residual stream: fp32 copy of the fp32 input
    hipMemcpyAsync(x_f32, xin, 738816ull * 4, hipMemcpyDeviceToDevice, stream);

    for (int l = 0; l < 12; ++l) {
        gemm_ln<0><<<dim3(18, 31), dim3(256), 0, stream>>>(
            x_f32, wt_qkv + (size_t)l * 1152 * 384, b_qkv + l * 1152,
            ln1g + l * 384, ln1b + l * 384,
            1924, 1152, nullptr, qbuf, kbuf, vtbuf);
        attn_k<<<dim3(61, 12), dim3(256), 0, stream>>>(
            qbuf, kbuf, vtbuf, attnout, (l == 11) ? attn_save : (float*)nullptr);
        gemm_sp<192><<<dim3(6, 31, 2), dim3(256), 0, stream>>>(
            attnout, 384, wt_proj + (size_t)l * 384 * 384, 384, b_proj + l * 384,
            1924, 384, x_f32);
        gemm_ln<2><<<dim3(24, 31), dim3(256), 0, stream>>>(
            x_f32, wt_fc1 + (size_t)l * 1536 * 384, b_fc1 + l * 1536,
            ln2g + l * 384, ln2b + l * 384,
            1924, 1536, mlp1, nullptr, nullptr, nullptr);
        gemm_sp<768><<<dim3(6, 31, 2), dim3(256), 0, stream>>>(
            mlp1, 1536, wt_fc2 + (size_t)l * 384 * 1536, 1536, b_fc2 + l * 384,
            1924, 384, x_f32);
    }
    ln_k<<<dim3(481), dim3(256), 0, stream>>>(x_f32, lnfg, lnfb, feats);
}

// Round 7
// 1060.747 us; speedup vs baseline: 1.6871x; 1.6871x over previous
//
#include <hip/hip_runtime.h>
#include <hip/hip_bf16.h>
#include <math.h>

typedef __bf16 bf16_t;
typedef __bf16 bf16x8 __attribute__((ext_vector_type(8)));
typedef float f32x4 __attribute__((ext_vector_type(4)));

#define NEGBIG -3.0e38f

// ---------------------------------------------------------------------------
// Weight transpose+convert: W [K][N] fp32  ->  Wt [N][K] bf16  (per layer z)
// ---------------------------------------------------------------------------
__global__ void __launch_bounds__(256) tr_k(
    const float* __restrict__ W, bf16_t* __restrict__ Wt, int K, int N)
{
    __shared__ float T[32][33];
    const size_t per = (size_t)K * N;
    const float* Wl = W + blockIdx.z * per;
    bf16_t* Wtl = Wt + blockIdx.z * per;
    int n0 = blockIdx.x * 32, k0 = blockIdx.y * 32;
    int tx = threadIdx.x & 31, ty = threadIdx.x >> 5;   // 32 x 8
#pragma unroll
    for (int i = 0; i < 4; ++i)
        T[ty + 8 * i][tx] = Wl[(size_t)(k0 + ty + 8 * i) * N + n0 + tx];
    __syncthreads();
#pragma unroll
    for (int i = 0; i < 4; ++i)
        Wtl[(size_t)(n0 + ty + 8 * i) * K + k0 + tx] = (bf16_t)T[tx][ty + 8 * i];
}

// ---------------------------------------------------------------------------
// bf16 MFMA GEMM (round-4 core): C[M,N] = A[M,K] * Bt[N,K]^T + bias
// 64x64 tile, 4 waves, BK=64 double-buffered LDS, one barrier per K-iter.
// MODE 0: QKV scatter; MODE 2: GELU(exact) -> bf16 store.
// ---------------------------------------------------------------------------
template <int MODE>
__global__ void __launch_bounds__(256) gemm_k(
    const bf16_t* __restrict__ A, const bf16_t* __restrict__ Bt,
    const float* __restrict__ bias, int M, int N, int K,
    bf16_t* __restrict__ outb,
    bf16_t* __restrict__ qb, bf16_t* __restrict__ kb, bf16_t* __restrict__ vtb)
{
    __shared__ alignas(16) bf16_t As[2][64][72];
    __shared__ alignas(16) bf16_t Bs[2][64][72];

    const int tid  = threadIdx.x;
    const int wave = tid >> 6, lane = tid & 63;
    const int m0 = blockIdx.y * 64, n0 = blockIdx.x * 64;
    const int rb = (wave >> 1) * 32, cb = (wave & 1) * 32;
    const int q4 = lane >> 4, mm = lane & 15;

    const int lrow = tid >> 3;         // 0..31
    const int lcol = (tid & 7) * 8;    // 0..56

    const bf16_t* pA0 = A  + (size_t)(m0 + lrow) * K + lcol;
    const bf16_t* pA1 = pA0 + (size_t)32 * K;
    const bf16_t* pB0 = Bt + (size_t)(n0 + lrow) * K + lcol;
    const bf16_t* pB1 = pB0 + (size_t)32 * K;

    f32x4 acc[2][2] = {};
    bf16x8 va0, va1, vb0, vb1;

    va0 = *(const bf16x8*)(pA0);
    va1 = *(const bf16x8*)(pA1);
    vb0 = *(const bf16x8*)(pB0);
    vb1 = *(const bf16x8*)(pB1);
    *(bf16x8*)(&As[0][lrow][lcol])      = va0;
    *(bf16x8*)(&As[0][lrow + 32][lcol]) = va1;
    *(bf16x8*)(&Bs[0][lrow][lcol])      = vb0;
    *(bf16x8*)(&Bs[0][lrow + 32][lcol]) = vb1;

    int cur = 0;
    for (int k0 = 0; k0 < K; k0 += 64) {
        __syncthreads();
        const bool has_next = (k0 + 64 < K);
        if (has_next) {
            va0 = *(const bf16x8*)(pA0 + k0 + 64);
            va1 = *(const bf16x8*)(pA1 + k0 + 64);
            vb0 = *(const bf16x8*)(pB0 + k0 + 64);
            vb1 = *(const bf16x8*)(pB1 + k0 + 64);
        }
#pragma unroll
        for (int kc = 0; kc < 64; kc += 32) {
            bf16x8 a0 = *(const bf16x8*)(&As[cur][rb + mm][kc + q4 * 8]);
            bf16x8 a1 = *(const bf16x8*)(&As[cur][rb + 16 + mm][kc + q4 * 8]);
            bf16x8 b0 = *(const bf16x8*)(&Bs[cur][cb + mm][kc + q4 * 8]);
            bf16x8 b1 = *(const bf16x8*)(&Bs[cur][cb + 16 + mm][kc + q4 * 8]);
            acc[0][0] = __builtin_amdgcn_mfma_f32_16x16x32_bf16(a0, b0, acc[0][0], 0, 0, 0);
            acc[0][1] = __builtin_amdgcn_mfma_f32_16x16x32_bf16(a0, b1, acc[0][1], 0, 0, 0);
            acc[1][0] = __builtin_amdgcn_mfma_f32_16x16x32_bf16(a1, b0, acc[1][0], 0, 0, 0);
            acc[1][1] = __builtin_amdgcn_mfma_f32_16x16x32_bf16(a1, b1, acc[1][1], 0, 0, 0);
        }
        if (has_next) {
            int nxt = cur ^ 1;
            *(bf16x8*)(&As[nxt][lrow][lcol])      = va0;
            *(bf16x8*)(&As[nxt][lrow + 32][lcol]) = va1;
            *(bf16x8*)(&Bs[nxt][lrow][lcol])      = vb0;
            *(bf16x8*)(&Bs[nxt][lrow + 32][lcol]) = vb1;
            cur = nxt;
        }
    }

#pragma unroll
    for (int i = 0; i < 2; ++i)
#pragma unroll
    for (int j = 0; j < 2; ++j) {
        int gc = n0 + cb + j * 16 + mm;
        float bv = bias[gc];
#pragma unroll
        for (int r = 0; r < 4; ++r) {
            int gr = m0 + rb + i * 16 + q4 * 4 + r;
            if (gr >= M) continue;
            float val = acc[i][j][r] + bv;
            if (MODE == 2) {
                float g = 0.5f * val * (1.0f + erff(val * 0.70710678118654752f));
                outb[(size_t)gr * N + gc] = (bf16_t)g;
            } else {  // QKV scatter
                int which = gc / 384, rem = gc % 384;
                int h = rem >> 6, d = rem & 63;
                int b = gr / 962, n = gr % 962;
                int bh = b * 6 + h;
                bf16_t bvv = (bf16_t)val;
                if (which == 0)      qb[((size_t)bh * 962 + n) * 64 + d] = bvv;
                else if (which == 1) kb[((size_t)bh * 962 + n) * 64 + d] = bvv;
                else                 vtb[((size_t)bh * 64 + d) * 992 + n] = bvv;
            }
        }
    }
}

// ---------------------------------------------------------------------------
// Split-K dbuf MFMA GEMM (proj / fc2): same BK=64 dbuf core; epilogue
// atomicAdd into fp32 residual (bias added by z==0 only).
// ---------------------------------------------------------------------------
template <int KLEN>
__global__ void __launch_bounds__(256) gemm_sp(
    const bf16_t* __restrict__ A, int lda,
    const bf16_t* __restrict__ Bt, int ldb,
    const float* __restrict__ bias, int M, int N,
    float* __restrict__ resid)
{
    __shared__ alignas(16) bf16_t As[2][64][72];
    __shared__ alignas(16) bf16_t Bs[2][64][72];

    const int tid  = threadIdx.x;
    const int wave = tid >> 6, lane = tid & 63;
    const int m0 = blockIdx.y * 64, n0 = blockIdx.x * 64;
    const int rb = (wave >> 1) * 32, cb = (wave & 1) * 32;
    const int q4 = lane >> 4, mm = lane & 15;
    const int ks = blockIdx.z * KLEN;

    const int lrow = tid >> 3;
    const int lcol = (tid & 7) * 8;

    const bf16_t* pA0 = A  + (size_t)(m0 + lrow) * lda + ks + lcol;
    const bf16_t* pA1 = pA0 + (size_t)32 * lda;
    const bf16_t* pB0 = Bt + (size_t)(n0 + lrow) * ldb + ks + lcol;
    const bf16_t* pB1 = pB0 + (size_t)32 * ldb;

    f32x4 acc[2][2] = {};
    bf16x8 va0, va1, vb0, vb1;

    va0 = *(const bf16x8*)(pA0);
    va1 = *(const bf16x8*)(pA1);
    vb0 = *(const bf16x8*)(pB0);
    vb1 = *(const bf16x8*)(pB1);
    *(bf16x8*)(&As[0][lrow][lcol])      = va0;
    *(bf16x8*)(&As[0][lrow + 32][lcol]) = va1;
    *(bf16x8*)(&Bs[0][lrow][lcol])      = vb0;
    *(bf16x8*)(&Bs[0][lrow + 32][lcol]) = vb1;

    int cur = 0;
    for (int k0 = 0; k0 < KLEN; k0 += 64) {
        __syncthreads();
        const bool has_next = (k0 + 64 < KLEN);
        if (has_next) {
            va0 = *(const bf16x8*)(pA0 + k0 + 64);
            va1 = *(const bf16x8*)(pA1 + k0 + 64);
            vb0 = *(const bf16x8*)(pB0 + k0 + 64);
            vb1 = *(const bf16x8*)(pB1 + k0 + 64);
        }
#pragma unroll
        for (int kc = 0; kc < 64; kc += 32) {
            bf16x8 a0 = *(const bf16x8*)(&As[cur][rb + mm][kc + q4 * 8]);
            bf16x8 a1 = *(const bf16x8*)(&As[cur][rb + 16 + mm][kc + q4 * 8]);
            bf16x8 b0 = *(const bf16x8*)(&Bs[cur][cb + mm][kc + q4 * 8]);
            bf16x8 b1 = *(const bf16x8*)(&Bs[cur][cb + 16 + mm][kc + q4 * 8]);
            acc[0][0] = __builtin_amdgcn_mfma_f32_16x16x32_bf16(a0, b0, acc[0][0], 0, 0, 0);
            acc[0][1] = __builtin_amdgcn_mfma_f32_16x16x32_bf16(a0, b1, acc[0][1], 0, 0, 0);
            acc[1][0] = __builtin_amdgcn_mfma_f32_16x16x32_bf16(a1, b0, acc[1][0], 0, 0, 0);
            acc[1][1] = __builtin_amdgcn_mfma_f32_16x16x32_bf16(a1, b1, acc[1][1], 0, 0, 0);
        }
        if (has_next) {
            int nxt = cur ^ 1;
            *(bf16x8*)(&As[nxt][lrow][lcol])      = va0;
            *(bf16x8*)(&As[nxt][lrow + 32][lcol]) = va1;
            *(bf16x8*)(&Bs[nxt][lrow][lcol])      = vb0;
            *(bf16x8*)(&Bs[nxt][lrow + 32][lcol]) = vb1;
            cur = nxt;
        }
    }

#pragma unroll
    for (int i = 0; i < 2; ++i)
#pragma unroll
    for (int j = 0; j < 2; ++j) {
        int gc = n0 + cb + j * 16 + mm;
        float bv = (blockIdx.z == 0) ? bias[gc] : 0.f;
#pragma unroll
        for (int r = 0; r < 4; ++r) {
            int gr = m0 + rb + i * 16 + q4 * 4 + r;
            if (gr >= M) continue;
            atomicAdd(&resid[(size_t)gr * N + gc], acc[i][j][r] + bv);
        }
    }
}

// ---------------------------------------------------------------------------
// Fused masked attention (vectorized stats). One WG per (bh, 16-row Q tile).
// ---------------------------------------------------------------------------
__global__ void __launch_bounds__(256) attn_k(
    const bf16_t* __restrict__ qb, const bf16_t* __restrict__ kb,
    const bf16_t* __restrict__ vtb, bf16_t* __restrict__ attnout,
    float* __restrict__ attn_save)
{
    __shared__ alignas(16) bf16_t S[16][1000];

    const int tid  = threadIdx.x;
    const int wave = tid >> 6, lane = tid & 63;
    const int q4 = lane >> 4, mm = lane & 15;
    const int bh = blockIdx.y, qt = blockIdx.x;
    const int qrow0 = qt * 16;

    int qr = qrow0 + mm; if (qr > 961) qr = 961;
    const bf16_t* qptr = qb + ((size_t)bh * 962 + qr) * 64 + q4 * 8;
    bf16x8 aq0 = *(const bf16x8*)(qptr);
    bf16x8 aq1 = *(const bf16x8*)(qptr + 32);

    for (int ct = wave; ct < 61; ct += 4) {
        int kr = ct * 16 + mm; if (kr > 961) kr = 961;
        const bf16_t* kptr = kb + ((size_t)bh * 962 + kr) * 64 + q4 * 8;
        bf16x8 b0 = *(const bf16x8*)(kptr);
        bf16x8 b1 = *(const bf16x8*)(kptr + 32);
        f32x4 acc = {};
        acc = __builtin_amdgcn_mfma_f32_16x16x32_bf16(aq0, b0, acc, 0, 0, 0);
        acc = __builtin_amdgcn_mfma_f32_16x16x32_bf16(aq1, b1, acc, 0, 0, 0);
        int col = ct * 16 + mm;
#pragma unroll
        for (int r = 0; r < 4; ++r) {
            int row = q4 * 4 + r;
            if (col < 962) S[row][col] = (bf16_t)(acc[r] * 0.125f);
        }
    }
    for (int idx = tid; idx < 16 * 38; idx += 256) {
        int r = idx / 38, c = 962 + idx % 38;
        S[r][c] = (bf16_t)NEGBIG;
    }
    __syncthreads();

    const int trow = tid >> 4, ti = tid & 15;
    float e[8][8];
    float mx = NEGBIG;
#pragma unroll
    for (int t = 0; t < 8; ++t) {
        int c8 = ti * 8 + 128 * t;
        bf16x8 xv;
        if (c8 < 1000) xv = *(const bf16x8*)(&S[trow][c8]);
        else {
#pragma unroll
            for (int j = 0; j < 8; ++j) xv[j] = (bf16_t)NEGBIG;
        }
#pragma unroll
        for (int j = 0; j < 8; ++j) { e[t][j] = (float)xv[j]; mx = fmaxf(mx, e[t][j]); }
    }
#pragma unroll
    for (int off = 8; off > 0; off >>= 1) mx = fmaxf(mx, __shfl_xor(mx, off, 16));

    float sum = 0.f;
#pragma unroll
    for (int t = 0; t < 8; ++t)
#pragma unroll
    for (int j = 0; j < 8; ++j) {
        float ev = __expf(e[t][j] - mx);
        e[t][j] = ev;
        if (ev >= 0.1f) sum += ev;
    }
#pragma unroll
    for (int off = 8; off > 0; off >>= 1) sum += __shfl_xor(sum, off, 16);
    float inv = 1.0f / sum;

    int row_g = qrow0 + trow;
#pragma unroll
    for (int t = 0; t < 8; ++t) {
        int c8 = ti * 8 + 128 * t;
        if (c8 >= 1000) continue;
        bf16x8 pv;
#pragma unroll
        for (int j = 0; j < 8; ++j) {
            float pp = (e[t][j] >= 0.1f) ? e[t][j] * inv : 0.f;
            e[t][j] = pp;
            pv[j] = (bf16_t)pp;
        }
        *(bf16x8*)(&S[trow][c8]) = pv;
        if (attn_save && row_g < 962) {
#pragma unroll
            for (int j = 0; j < 8; ++j)
                if (c8 + j < 962)
                    attn_save[((size_t)bh * 962 + row_g) * 962 + c8 + j] = e[t][j];
        }
    }
    __syncthreads();

    const int wc0 = wave * 16;
    f32x4 o = {};
    for (int kc = 0; kc < 31; ++kc) {
        bf16x8 pa = *(const bf16x8*)(&S[mm][kc * 32 + q4 * 8]);
        bf16x8 vb = *(const bf16x8*)(vtb + ((size_t)bh * 64 + wc0 + mm) * 992 + kc * 32 + q4 * 8);
        o = __builtin_amdgcn_mfma_f32_16x16x32_bf16(pa, vb, o, 0, 0, 0);
    }
    int b = bh / 6, h = bh % 6;
#pragma unroll
    for (int r = 0; r < 4; ++r) {
        int qrr = qrow0 + q4 * 4 + r;
        if (qrr < 962)
            attnout[((size_t)(b * 962 + qrr)) * 384 + h * 64 + wc0 + mm] = (bf16_t)o[r];
    }
}

// ---------------------------------------------------------------------------
// LayerNorm: one wave per token, fp32 in/params, templated output dtype
// ---------------------------------------------------------------------------
template <typename OT>
__global__ void __launch_bounds__(256) ln_k(
    const float* __restrict__ x, const float* __restrict__ g,
    const float* __restrict__ b, OT* __restrict__ out)
{
    int t = blockIdx.x * 4 + (threadIdx.x >> 6);
    int lane = threadIdx.x & 63;
    const float* xp = x + (size_t)t * 384;
    float v[6];
    float s = 0.f;
#pragma unroll
    for (int i = 0; i < 6; ++i) { v[i] = xp[lane + 64 * i]; s += v[i]; }
    for (int off = 32; off > 0; off >>= 1) s += __shfl_xor(s, off);
    float mean = s * (1.0f / 384.0f);
    float s2 = 0.f;
#pragma unroll
    for (int i = 0; i < 6; ++i) { float d = v[i] - mean; s2 += d * d; }
    for (int off = 32; off > 0; off >>= 1) s2 += __shfl_xor(s2, off);
    float rstd = rsqrtf(s2 * (1.0f / 384.0f) + 1e-6f);
#pragma unroll
    for (int i = 0; i < 6; ++i) {
        int c = lane + 64 * i;
        float y = (v[i] - mean) * rstd * g[c] + b[c];
        out[(size_t)t * 384 + c] = (OT)y;
    }
}

// ---------------------------------------------------------------------------
extern "C" void kernel_launch(void* const* d_in, const int* in_sizes, int n_in,
                              void* d_out, int out_size, void* d_ws, size_t ws_size,
                              hipStream_t stream)
{
    const float* xin    = (const float*)d_in[0];
    const float* w_qkv  = (const float*)d_in[1];
    const float* b_qkv  = (const float*)d_in[2];
    const float* w_proj = (const float*)d_in[3];
    const float* b_proj = (const float*)d_in[4];
    const float* ln1g   = (const float*)d_in[5];
    const float* ln1b   = (const float*)d_in[6];
    const float* ln2g   = (const float*)d_in[7];
    const float* ln2b   = (const float*)d_in[8];
    const float* w_fc1  = (const float*)d_in[9];
    const float* b_fc1  = (const float*)d_in[10];
    const float* w_fc2  = (const float*)d_in[11];
    const float* b_fc2  = (const float*)d_in[12];
    const float* lnfg   = (const float*)d_in[13];
    const float* lnfb   = (const float*)d_in[14];

    float* feats     = (float*)d_out;
    float* attn_save = feats + 738816;   // 2*962*384

    char* p = (char*)d_ws;
    auto alloc = [&](size_t bytes) {
        char* r = p;
        p += (bytes + 255) & ~(size_t)255;
        return r;
    };
    float*  x_f32   = (float*)alloc(1924ull * 384 * 4);
    bf16_t* xn      = (bf16_t*)alloc(1984ull * 384 * 2);    // rows padded to 64x
    bf16_t* qbuf    = (bf16_t*)alloc(12ull * 962 * 64 * 2);
    bf16_t* kbuf    = (bf16_t*)alloc(12ull * 962 * 64 * 2);
    bf16_t* vtbuf   = (bf16_t*)alloc(12ull * 64 * 992 * 2);
    bf16_t* attnout = (bf16_t*)alloc(1984ull * 384 * 2);    // rows padded
    bf16_t* mlp1    = (bf16_t*)alloc(1984ull * 1536 * 2);   // rows padded
    bf16_t* wt_qkv  = (bf16_t*)alloc(12ull * 1152 * 384 * 2);
    bf16_t* wt_proj = (bf16_t*)alloc(12ull * 384 * 384 * 2);
    bf16_t* wt_fc1  = (bf16_t*)alloc(12ull * 1536 * 384 * 2);
    bf16_t* wt_fc2  = (bf16_t*)alloc(12ull * 384 * 1536 * 2);

    // one-time per launch: weights -> bf16, transposed to [N][K]
    tr_k<<<dim3(36, 12, 12), dim3(256), 0, stream>>>(w_qkv,  wt_qkv,  384, 1152);
    tr_k<<<dim3(12, 12, 12), dim3(256), 0, stream>>>(w_proj, wt_proj, 384, 384);
    tr_k<<<dim3(48, 12, 12), dim3(256), 0, stream>>>(w_fc1,  wt_fc1,  384, 1536);
    tr_k<<<dim3(12, 48, 12), dim3(256), 0, stream>>>(w_fc2,  wt_fc2,  1536, 384);

    // residual stream: fp32 copy of the fp32 input
    hipMemcpyAsync(x_f32, xin, 738816ull * 4, hipMemcpyDeviceToDevice, stream);

    for (int l = 0; l < 12; ++l) {
        ln_k<bf16_t><<<dim3(481), dim3(256), 0, stream>>>(x_f32, ln1g + l * 384, ln1b + l * 384, xn);
        gemm_k<0><<<dim3(18, 31), dim3(256), 0, stream>>>(
            xn, wt_qkv + (size_t)l * 1152 * 384, b_qkv + l * 1152,
            1924, 1152, 384, nullptr, qbuf, kbuf, vtbuf);
        attn_k<<<dim3(61, 12), dim3(256), 0, stream>>>(
            qbuf, kbuf, vtbuf, attnout, (l == 11) ? attn_save : (float*)nullptr);
        gemm_sp<192><<<dim3(6, 31, 2), dim3(256), 0, stream>>>(
            attnout, 384, wt_proj + (size_t)l * 384 * 384, 384, b_proj + l * 384,
            1924, 384, x_f32);
        ln_k<bf16_t><<<dim3(481), dim3(256), 0, stream>>>(x_f32, ln2g + l * 384, ln2b + l * 384, xn);
        gemm_k<2><<<dim3(24, 31), dim3(256), 0, stream>>>(
            xn, wt_fc1 + (size_t)l * 1536 * 384, b_fc1 + l * 1536,
            1924, 1536, 384, mlp1, nullptr, nullptr, nullptr);
        gemm_sp<384><<<dim3(6, 31, 4), dim3(256), 0, stream>>>(
            mlp1, 1536, wt_fc2 + (size_t)l * 384 * 1536, 1536, b_fc2 + l * 384,
            1924, 384, x_f32);
    }
    ln_k<float><<<dim3(481), dim3(256), 0, stream>>>(x_f32, lnfg, lnfb, feats);
}